// Round 16
// baseline (84.499 us; speedup 1.0000x reference)
//
#include <hip/hip_runtime.h>
#include <cstdint>
#include <cstddef>

#define NN 4096
#define FDIM 512
#define HDIM 64
#define NHEAD 8
#define CDIM 40
#define MAXD 256   // max neighbors kept per row (~41 expected)

typedef __attribute__((ext_vector_type(8))) short bf16x8;
typedef __attribute__((ext_vector_type(16))) float f32x16;

__device__ __forceinline__ float wave_max64(float v) {
  for (int o = 32; o; o >>= 1) v = fmaxf(v, __shfl_xor(v, o));
  return v;
}
__device__ __forceinline__ float wave_sum64(float v) {
  for (int o = 32; o; o >>= 1) v += __shfl_xor(v, o);
  return v;
}
__device__ __forceinline__ float readlane_f(float v, int sl) {
  return __uint_as_float((unsigned)__builtin_amdgcn_readlane((int)__float_as_uint(v), sl));
}
__device__ __forceinline__ int readlane_i(int v, int sl) {
  return __builtin_amdgcn_readlane(v, sl);
}
// fp32 -> bf16 (RNE) and back, via bit ops
__device__ __forceinline__ unsigned short f2bf(float x) {
  unsigned u = __float_as_uint(x);
  return (unsigned short)((u + 0x7fffu + ((u >> 16) & 1u)) >> 16);
}
__device__ __forceinline__ float bf2f(unsigned short b) {
  return __uint_as_float(((unsigned)b) << 16);
}
// unpack packed bf16 pair (int) -> floats
__device__ __forceinline__ float lo16f(int u) { return __int_as_float(u << 16); }
__device__ __forceinline__ float hi16f(int u) { return __int_as_float(u & 0xffff0000); }
// 8 fp32 -> 8 bf16 hi + 8 bf16 lo, packed
__device__ __forceinline__ void cvt8(const float4& a, const float4& b,
                                     int4& hi, int4& lo) {
  unsigned short h0 = f2bf(a.x), h1 = f2bf(a.y), h2 = f2bf(a.z), h3 = f2bf(a.w);
  unsigned short h4 = f2bf(b.x), h5 = f2bf(b.y), h6 = f2bf(b.z), h7 = f2bf(b.w);
  hi = make_int4((int)((unsigned)h0 | ((unsigned)h1 << 16)),
                 (int)((unsigned)h2 | ((unsigned)h3 << 16)),
                 (int)((unsigned)h4 | ((unsigned)h5 << 16)),
                 (int)((unsigned)h6 | ((unsigned)h7 << 16)));
  unsigned short l0 = f2bf(a.x - bf2f(h0)), l1 = f2bf(a.y - bf2f(h1));
  unsigned short l2 = f2bf(a.z - bf2f(h2)), l3 = f2bf(a.w - bf2f(h3));
  unsigned short l4 = f2bf(b.x - bf2f(h4)), l5 = f2bf(b.y - bf2f(h5));
  unsigned short l6 = f2bf(b.z - bf2f(h6)), l7 = f2bf(b.w - bf2f(h7));
  lo = make_int4((int)((unsigned)l0 | ((unsigned)l1 << 16)),
                 (int)((unsigned)l2 | ((unsigned)l3 << 16)),
                 (int)((unsigned)l4 | ((unsigned)l5 << 16)),
                 (int)((unsigned)l6 | ((unsigned)l7 << 16)));
}

// ---------------- Kernel 1: prep (weight conversions only) -----------------
__global__ __launch_bounds__(256) void k_prep(
    const float* __restrict__ W1, short* __restrict__ Bhi, short* __restrict__ Blo,
    const float* __restrict__ W2, short* __restrict__ W2thi, short* __restrict__ W2tlo,
    const float* __restrict__ Wo1, short* __restrict__ Wo1thi, short* __restrict__ Wo1tlo) {
  __shared__ float T[64][65];
  int bx = blockIdx.x, tid = threadIdx.x;
  if (bx < 64) {       // ---- W1 tile transpose + bf16 hi/lo: [k][n] -> [n][k]
    int h = bx >> 3, kb = bx & 7;
    const float* src = W1 + ((size_t)h * FDIM + kb * 64) * HDIM;
#pragma unroll
    for (int q = 0; q < 4; ++q) {
      int fi = q * 256 + tid, kk = fi >> 4, n4 = fi & 15;
      float4 v = *(const float4*)(src + (size_t)kk * HDIM + n4 * 4);
      T[n4 * 4 + 0][kk] = v.x; T[n4 * 4 + 1][kk] = v.y;
      T[n4 * 4 + 2][kk] = v.z; T[n4 * 4 + 3][kk] = v.w;
    }
    __syncthreads();
#pragma unroll
    for (int q = 0; q < 4; ++q) {
      int fi = q * 256 + tid, n = fi >> 4, k4 = fi & 15;
      float a = T[n][k4 * 4], b = T[n][k4 * 4 + 1];
      float c = T[n][k4 * 4 + 2], d = T[n][k4 * 4 + 3];
      size_t o = ((size_t)h * 64 + n) * FDIM + kb * 64 + k4 * 4;
      unsigned short ha = f2bf(a), hb = f2bf(b), hc = f2bf(c), hd = f2bf(d);
      *(short4*)(Bhi + o) = make_short4((short)ha, (short)hb, (short)hc, (short)hd);
      *(short4*)(Blo + o) = make_short4((short)f2bf(a - bf2f(ha)), (short)f2bf(b - bf2f(hb)),
                                        (short)f2bf(c - bf2f(hc)), (short)f2bf(d - bf2f(hd)));
    }
    return;
  }
  bx -= 64;
  if (bx < 8) {        // ---- W2[h] transpose [64k][64n] -> [n][k] hi/lo
    int h = bx;
    const float* src = W2 + (size_t)h * HDIM * HDIM;
#pragma unroll
    for (int q = 0; q < 4; ++q) {
      int fi = q * 256 + tid, kk = fi >> 4, n4 = fi & 15;
      float4 v = *(const float4*)(src + (size_t)kk * HDIM + n4 * 4);
      T[n4 * 4 + 0][kk] = v.x; T[n4 * 4 + 1][kk] = v.y;
      T[n4 * 4 + 2][kk] = v.z; T[n4 * 4 + 3][kk] = v.w;
    }
    __syncthreads();
#pragma unroll
    for (int q = 0; q < 4; ++q) {
      int fi = q * 256 + tid, n = fi >> 4, k4 = fi & 15;
      float a = T[n][k4 * 4], b = T[n][k4 * 4 + 1];
      float c = T[n][k4 * 4 + 2], d = T[n][k4 * 4 + 3];
      size_t o = (size_t)h * 4096 + (size_t)n * 64 + k4 * 4;
      unsigned short ha = f2bf(a), hb = f2bf(b), hc = f2bf(c), hd = f2bf(d);
      *(short4*)(W2thi + o) = make_short4((short)ha, (short)hb, (short)hc, (short)hd);
      *(short4*)(W2tlo + o) = make_short4((short)f2bf(a - bf2f(ha)), (short)f2bf(b - bf2f(hb)),
                                          (short)f2bf(c - bf2f(hc)), (short)f2bf(d - bf2f(hd)));
    }
    return;
  }
  bx -= 8;
  {                    // ---- Wo1 transpose+pad [512][40] -> [64][512] hi/lo
#pragma unroll
    for (int q = 0; q < 16; ++q) {
      int idx = q * 256 + tid;          // 0..4095
      int n = bx * 8 + (idx >> 9), k = idx & 511;
      float v = (n < CDIM) ? Wo1[(size_t)k * CDIM + n] : 0.f;
      unsigned short hv = f2bf(v);
      Wo1thi[(size_t)n * FDIM + k] = (short)hv;
      Wo1tlo[(size_t)n * FDIM + k] = (short)f2bf(v - bf2f(hv));
    }
  }
}

// ---------------- Kernel 2: MFMA GEMM (BK=32, 24KB LDS) + f1/f2  ∥  CSR ----
// LDS 48->24KB doubles co-residency (3->6 blocks/CU) for both the CSR
// bias stream (latency hiding) and GEMM overlap.
__global__ __launch_bounds__(256) void k_gemm(
    const float* __restrict__ seq,
    const short* __restrict__ Bhi, const short* __restrict__ Blo,
    const float* __restrict__ a1, const float* __restrict__ b1,
    const float* __restrict__ a2, const float* __restrict__ b2,
    short* __restrict__ FTSb, float* __restrict__ F1t, float* __restrict__ F2t,
    const float* __restrict__ bias, int* __restrict__ nbr, int* __restrict__ cnt) {
  __shared__ short AH[2][64][16], AL[2][64][16];    // [kstep16][m][k-slot] 8KB
  __shared__ short BH[2][128][16], BL[2][128][16];  // [kstep16][n][k-slot] 16KB
  __shared__ int wtot[4];
  const int bx = blockIdx.x;
  const int tid = threadIdx.x, lane = tid & 63, w = tid >> 6;

  if (bx >= 256) {     // ---------------- CSR: one block per row ------------
    int row = bx - 256;
    int wv = w;
    const float4* r = (const float4*)(bias + (size_t)row * NN);
    unsigned mask = 0;
#pragma unroll
    for (int i = 0; i < 4; ++i) {
      float4 v = r[tid * 4 + i];
      mask |= (unsigned)((v.x == 0.f ? 1 : 0) | (v.y == 0.f ? 2 : 0) |
                         (v.z == 0.f ? 4 : 0) | (v.w == 0.f ? 8 : 0)) << (i * 4);
    }
    int c = __popc(mask);
    int pre = c;
#pragma unroll
    for (int o = 1; o < 64; o <<= 1) {
      int u = __shfl_up(pre, o);
      if (lane >= o) pre += u;
    }
    if (lane == 63) wtot[wv] = pre;
    __syncthreads();
    int woff = 0;
#pragma unroll
    for (int ww = 0; ww < 4; ++ww)
      if (ww < wv) woff += wtot[ww];
    int excl = woff + pre - c;
    int* outp = nbr + (size_t)row * MAXD;
    int col0 = tid * 16, k = 0;
#pragma unroll
    for (int i = 0; i < 16; ++i) {
      if ((mask >> i) & 1) {
        int p = excl + k;
        if (p < MAXD) outp[p] = col0 + i;
        ++k;
      }
    }
    if (tid == 0) {
      int total = wtot[0] + wtot[1] + wtot[2] + wtot[3];
      cnt[row] = total < MAXD ? total : MAXD;
    }
    return;
  }

  // ---------------- GEMM tile ----------------
  const int mtile = bx & 63, npair = bx >> 6;
  const int wm = w >> 1, wn = w & 1;
  const int ml = lane & 31, g = lane >> 5, g8 = g * 8;

  f32x16 acc0, acc1;
#pragma unroll
  for (int r = 0; r < 16; ++r) { acc0[r] = 0.f; acc1[r] = 0.f; }

  const short* Bbh = Bhi + (((size_t)npair * 128) << 9);
  const short* Bbl = Blo + (((size_t)npair * 128) << 9);

  // staging coords: A row tn (0..63), 8 k per thread; B rows tn, tn+64
  const int tn = tid >> 2, k4 = tid & 3;
  const int ks = k4 >> 1, ko = (k4 & 1) * 8;
  const size_t so = ((size_t)tn << 9) + (size_t)k4 * 8;
  const float* As0 = seq + (((size_t)(mtile * 64 + tn)) << 9) + k4 * 8;

  float4 fa0a, fa0b;
  int4 rbh0, rbh1, rbl0, rbl1;
  {
    fa0a = *(const float4*)(As0);      fa0b = *(const float4*)(As0 + 4);
    rbh0 = *(const int4*)(Bbh + so);              rbl0 = *(const int4*)(Bbl + so);
    rbh1 = *(const int4*)(Bbh + so + (64 << 9));  rbl1 = *(const int4*)(Bbl + so + (64 << 9));
  }

  const int NCH = FDIM / 32;   // 16 chunks of 32 k
  for (int c = 0; c < NCH; ++c) {
    {
      int4 hi0, lo0;
      cvt8(fa0a, fa0b, hi0, lo0);
      *(int4*)&AH[ks][tn][ko] = hi0;  *(int4*)&AL[ks][tn][ko] = lo0;
    }
    *(int4*)&BH[ks][tn][ko] = rbh0;       *(int4*)&BL[ks][tn][ko] = rbl0;
    *(int4*)&BH[ks][64 + tn][ko] = rbh1;  *(int4*)&BL[ks][64 + tn][ko] = rbl1;
    __syncthreads();
    if (c + 1 < NCH) {
      size_t o = so + (size_t)(c + 1) * 32;
      const float* a0 = As0 + (size_t)(c + 1) * 32;
      fa0a = *(const float4*)(a0);      fa0b = *(const float4*)(a0 + 4);
      rbh0 = *(const int4*)(Bbh + o);              rbl0 = *(const int4*)(Bbl + o);
      rbh1 = *(const int4*)(Bbh + o + (64 << 9));  rbl1 = *(const int4*)(Bbl + o + (64 << 9));
    }
#pragma unroll
    for (int t = 0; t < 2; ++t) {
      bf16x8 ah = *(const bf16x8*)&AH[t][wm * 32 + ml][g8];
      bf16x8 al = *(const bf16x8*)&AL[t][wm * 32 + ml][g8];
      bf16x8 bh0 = *(const bf16x8*)&BH[t][wn * 64 + ml][g8];
      bf16x8 bl0 = *(const bf16x8*)&BL[t][wn * 64 + ml][g8];
      acc0 = __builtin_amdgcn_mfma_f32_32x32x16_bf16(ah, bh0, acc0, 0, 0, 0);
      acc0 = __builtin_amdgcn_mfma_f32_32x32x16_bf16(al, bh0, acc0, 0, 0, 0);
      acc0 = __builtin_amdgcn_mfma_f32_32x32x16_bf16(ah, bl0, acc0, 0, 0, 0);
      bf16x8 bh1 = *(const bf16x8*)&BH[t][wn * 64 + 32 + ml][g8];
      bf16x8 bl1 = *(const bf16x8*)&BL[t][wn * 64 + 32 + ml][g8];
      acc1 = __builtin_amdgcn_mfma_f32_32x32x16_bf16(ah, bh1, acc1, 0, 0, 0);
      acc1 = __builtin_amdgcn_mfma_f32_32x32x16_bf16(al, bh1, acc1, 0, 0, 0);
      acc1 = __builtin_amdgcn_mfma_f32_32x32x16_bf16(ah, bl1, acc1, 0, 0, 0);
    }
    __syncthreads();
  }

  // epilogue: C layout col=lane&31, row=(r&3)+8*(r>>2)+4*(lane>>5)
  const int h = npair * 2 + wn;
  const float a1lo = a1[h * 64 + ml], a1hi = a1[h * 64 + 32 + ml];
  const float a2lo = a2[h * 64 + ml], a2hi = a2[h * 64 + 32 + ml];
  const float b1h = b1[h], b2h = b2[h];
  const int row0 = mtile * 64 + wm * 32 + 4 * g;
  const int col0 = npair * 128 + wn * 64 + ml;
#pragma unroll
  for (int r = 0; r < 16; ++r) {
    int row = row0 + (r & 3) + 8 * (r >> 2);
    FTSb[(size_t)row * FDIM + col0] = (short)f2bf(acc0[r]);
    FTSb[(size_t)row * FDIM + col0 + 32] = (short)f2bf(acc1[r]);
    float p1 = acc0[r] * a1lo + acc1[r] * a1hi;
    float p2 = acc0[r] * a2lo + acc1[r] * a2hi;
#pragma unroll
    for (int o = 1; o < 32; o <<= 1) {
      p1 += __shfl_xor(p1, o);
      p2 += __shfl_xor(p2, o);
    }
    if (ml == 0) {
      F1t[(size_t)row * 8 + h] = p1 + b1h;
      F2t[(size_t)row * 8 + h] = p2 + b2h;
    }
  }
}

// ---------------- Kernel 3: sparse softmax + aggregation (1 wave/row) -------
__global__ __launch_bounds__(256) void k_agg1(
    const short* __restrict__ FTSb, const float* __restrict__ F1t,
    const float* __restrict__ F2t, const int* __restrict__ nbr,
    const int* __restrict__ cnt, short* __restrict__ VALShi,
    short* __restrict__ VALSlo) {
  __shared__ float plds[4][MAXD][8];   // [wave][slot][head] = 32 KB
  int wv = threadIdx.x >> 6, lane = threadIdx.x & 63;
  int i = blockIdx.x * 4 + wv;
  int deg = cnt[i];
  const int* nb = nbr + (size_t)i * MAXD;
  float4 f1a = *(const float4*)(F1t + (size_t)i * 8);
  float4 f1b = *(const float4*)(F1t + (size_t)i * 8 + 4);

  float4 pa[4], pb[4];
  int jreg[4];
  float m0 = -1e30f, m1 = -1e30f, m2 = -1e30f, m3 = -1e30f;
  float m4 = -1e30f, m5 = -1e30f, m6 = -1e30f, m7 = -1e30f;
#pragma unroll
  for (int r = 0; r < 4; ++r) {
    int t = r * 64 + lane;
    jreg[r] = 0;
    pa[r] = make_float4(-1e30f, -1e30f, -1e30f, -1e30f);
    pb[r] = pa[r];
    if (t < deg) {
      int j = nb[t];
      jreg[r] = j;
      float4 f2a = *(const float4*)(F2t + (size_t)j * 8);
      float4 f2b = *(const float4*)(F2t + (size_t)j * 8 + 4);
      float4 xa, xb;
      xa.x = f1a.x + f2a.x; xa.x = xa.x >= 0.f ? xa.x : 0.2f * xa.x;
      xa.y = f1a.y + f2a.y; xa.y = xa.y >= 0.f ? xa.y : 0.2f * xa.y;
      xa.z = f1a.z + f2a.z; xa.z = xa.z >= 0.f ? xa.z : 0.2f * xa.z;
      xa.w = f1a.w + f2a.w; xa.w = xa.w >= 0.f ? xa.w : 0.2f * xa.w;
      xb.x = f1b.x + f2b.x; xb.x = xb.x >= 0.f ? xb.x : 0.2f * xb.x;
      xb.y = f1b.y + f2b.y; xb.y = xb.y >= 0.f ? xb.y : 0.2f * xb.y;
      xb.z = f1b.z + f2b.z; xb.z = xb.z >= 0.f ? xb.z : 0.2f * xb.z;
      xb.w = f1b.w + f2b.w; xb.w = xb.w >= 0.f ? xb.w : 0.2f * xb.w;
      pa[r] = xa; pb[r] = xb;
      m0 = fmaxf(m0, xa.x); m1 = fmaxf(m1, xa.y);
      m2 = fmaxf(m2, xa.z); m3 = fmaxf(m3, xa.w);
      m4 = fmaxf(m4, xb.x); m5 = fmaxf(m5, xb.y);
      m6 = fmaxf(m6, xb.z); m7 = fmaxf(m7, xb.w);
    }
  }
  m0 = wave_max64(m0); m1 = wave_max64(m1); m2 = wave_max64(m2); m3 = wave_max64(m3);
  m4 = wave_max64(m4); m5 = wave_max64(m5); m6 = wave_max64(m6); m7 = wave_max64(m7);
  float s0 = 0.f, s1 = 0.f, s2 = 0.f, s3 = 0.f, s4 = 0.f, s5 = 0.f, s6 = 0.f, s7 = 0.f;
#pragma unroll
  for (int r = 0; r < 4; ++r) {
    int t = r * 64 + lane;
    float4 ea = make_float4(0.f, 0.f, 0.f, 0.f), eb = ea;
    if (t < deg) {
      ea.x = __expf(pa[r].x - m0); ea.y = __expf(pa[r].y - m1);
      ea.z = __expf(pa[r].z - m2); ea.w = __expf(pa[r].w - m3);
      eb.x = __expf(pb[r].x - m4); eb.y = __expf(pb[r].y - m5);
      eb.z = __expf(pb[r].z - m6); eb.w = __expf(pb[r].w - m7);
      *(float4*)&plds[wv][t][0] = ea;
      *(float4*)&plds[wv][t][4] = eb;
    }
    s0 += ea.x; s1 += ea.y; s2 += ea.z; s3 += ea.w;
    s4 += eb.x; s5 += eb.y; s6 += eb.z; s7 += eb.w;
  }
  s0 = wave_sum64(s0); s1 = wave_sum64(s1); s2 = wave_sum64(s2); s3 = wave_sum64(s3);
  s4 = wave_sum64(s4); s5 = wave_sum64(s5); s6 = wave_sum64(s6); s7 = wave_sum64(s7);

  const int q = lane >> 3;   // head for this lane's 8 features
  float sq = (q < 4) ? (q < 2 ? (q == 0 ? s0 : s1) : (q == 2 ? s2 : s3))
                     : (q < 6 ? (q == 4 ? s4 : s5) : (q == 6 ? s6 : s7));
  float inv = 1.f / sq;

  float4 aA = make_float4(0.f, 0.f, 0.f, 0.f), bA = aA;
  float4 aB = aA, bB = aA, aC = aA, bC = aA, aD = aA, bD = aA;
  const size_t lo8 = (size_t)lane * 8;
#pragma unroll
  for (int r = 0; r < 4; ++r) {
    int base = r * 64;
    if (base >= deg) break;
    int lim = deg - base;
    lim = lim < 64 ? lim : 64;
    int sl = 0;
    for (; sl + 4 <= lim; sl += 4) {
      int j0 = readlane_i(jreg[r], sl);
      int j1 = readlane_i(jreg[r], sl + 1);
      int j2 = readlane_i(jreg[r], sl + 2);
      int j3 = readlane_i(jreg[r], sl + 3);
      float w0 = plds[wv][base + sl][q];
      float w1 = plds[wv][base + sl + 1][q];
      float w2 = plds[wv][base + sl + 2][q];
      float w3 = plds[wv][base + sl + 3][q];
      int4 g0 = *(const int4*)(FTSb + (size_t)j0 * FDIM + lo8);
      int4 g1 = *(const int4*)(FTSb + (size_t)j1 * FDIM + lo8);
      int4 g2 = *(const int4*)(FTSb + (size_t)j2 * FDIM + lo8);
      int4 g3 = *(const int4*)(FTSb + (size_t)j3 * FDIM + lo8);
      aA.x += w0 * lo16f(g0.x); aA.y += w0 * hi16f(g0.x);
      aA.z += w0 * lo16f(g0.y); aA.w += w0 * hi16f(g0.y);
      bA.x += w0 * lo16f(g0.z); bA.y += w0 * hi16f(g0.z);
      bA.z += w0 * lo16f(g0.w); bA.w += w0 * hi16f(g0.w);
      aB.x += w1 * lo16f(g1.x); aB.y += w1 * hi16f(g1.x);
      aB.z += w1 * lo16f(g1.y); aB.w += w1 * hi16f(g1.y);
      bB.x += w1 * lo16f(g1.z); bB.y += w1 * hi16f(g1.z);
      bB.z += w1 * lo16f(g1.w); bB.w += w1 * hi16f(g1.w);
      aC.x += w2 * lo16f(g2.x); aC.y += w2 * hi16f(g2.x);
      aC.z += w2 * lo16f(g2.y); aC.w += w2 * hi16f(g2.y);
      bC.x += w2 * lo16f(g2.z); bC.y += w2 * hi16f(g2.z);
      bC.z += w2 * lo16f(g2.w); bC.w += w2 * hi16f(g2.w);
      aD.x += w3 * lo16f(g3.x); aD.y += w3 * hi16f(g3.x);
      aD.z += w3 * lo16f(g3.y); aD.w += w3 * hi16f(g3.y);
      bD.x += w3 * lo16f(g3.z); bD.y += w3 * hi16f(g3.z);
      bD.z += w3 * lo16f(g3.w); bD.w += w3 * hi16f(g3.w);
    }
    for (; sl < lim; ++sl) {
      int j0 = readlane_i(jreg[r], sl);
      float w0 = plds[wv][base + sl][q];
      int4 g0 = *(const int4*)(FTSb + (size_t)j0 * FDIM + lo8);
      aA.x += w0 * lo16f(g0.x); aA.y += w0 * hi16f(g0.x);
      aA.z += w0 * lo16f(g0.y); aA.w += w0 * hi16f(g0.y);
      bA.x += w0 * lo16f(g0.z); bA.y += w0 * hi16f(g0.z);
      bA.z += w0 * lo16f(g0.w); bA.w += w0 * hi16f(g0.w);
    }
  }
  float v0 = (aA.x + aB.x + aC.x + aD.x) * inv;
  float v1 = (aA.y + aB.y + aC.y + aD.y) * inv;
  float v2 = (aA.z + aB.z + aC.z + aD.z) * inv;
  float v3 = (aA.w + aB.w + aC.w + aD.w) * inv;
  float v4 = (bA.x + bB.x + bC.x + bD.x) * inv;
  float v5 = (bA.y + bB.y + bC.y + bD.y) * inv;
  float v6 = (bA.z + bB.z + bC.z + bD.z) * inv;
  float v7 = (bA.w + bB.w + bC.w + bD.w) * inv;
  unsigned short h0 = f2bf(v0), h1 = f2bf(v1), h2 = f2bf(v2), h3 = f2bf(v3);
  unsigned short h4 = f2bf(v4), h5 = f2bf(v5), h6 = f2bf(v6), h7 = f2bf(v7);
  *(int4*)(VALShi + (size_t)i * FDIM + lo8) = make_int4(
      (int)((unsigned)h0 | ((unsigned)h1 << 16)), (int)((unsigned)h2 | ((unsigned)h3 << 16)),
      (int)((unsigned)h4 | ((unsigned)h5 << 16)), (int)((unsigned)h6 | ((unsigned)h7 << 16)));
  unsigned short l0 = f2bf(v0 - bf2f(h0)), l1 = f2bf(v1 - bf2f(h1));
  unsigned short l2 = f2bf(v2 - bf2f(h2)), l3 = f2bf(v3 - bf2f(h3));
  unsigned short l4 = f2bf(v4 - bf2f(h4)), l5 = f2bf(v5 - bf2f(h5));
  unsigned short l6 = f2bf(v6 - bf2f(h6)), l7 = f2bf(v7 - bf2f(h7));
  *(int4*)(VALSlo + (size_t)i * FDIM + lo8) = make_int4(
      (int)((unsigned)l0 | ((unsigned)l1 << 16)), (int)((unsigned)l2 | ((unsigned)l3 << 16)),
      (int)((unsigned)l4 | ((unsigned)l5 << 16)), (int)((unsigned)l6 | ((unsigned)l7 << 16)));
}

// ---------------- Kernel 4: split tail: per head-group partial FTS2/F1O/F2O -
__global__ __launch_bounds__(256) void k_tail(
    const short* __restrict__ VALShi, const short* __restrict__ VALSlo,
    const short* __restrict__ W2thi, const short* __restrict__ W2tlo,
    const float* __restrict__ bW,
    const short* __restrict__ Wo1thi, const short* __restrict__ Wo1tlo,
    const float* __restrict__ ao1, const float* __restrict__ ao2,
    float* __restrict__ FTS2, float* __restrict__ F1O, float* __restrict__ F2O) {
  __shared__ short AH[4][64][16], AL[4][64][16];   // VALS tile (A of W2 mfma)
  __shared__ short BH[4][64][16], BL[4][64][16];   // W2t[h]    (B of W2 mfma)
  __shared__ short CH[4][64][16], CL[4][64][16];   // H1_h      (A of fts2 mfma)
  __shared__ short DH[4][64][16], DL[4][64][16];   // Wo1t[h]   (B of fts2 mfma)
  __shared__ float p1buf[2][64], p2buf[2][64];
  const int bx = blockIdx.x;
  const int i0 = (bx >> 1) * 64;
  const int hg = bx & 1;
  const int tid = threadIdx.x, lane = tid & 63, w = tid >> 6;
  const int wm = w >> 1, wn = w & 1;
  const int ml = lane & 31, g = lane >> 5, g8 = g * 8;
  const int tn = tid >> 2, k8 = tid & 3;
  const int colw = wn * 32 + ml;
  const int rowl0 = wm * 32 + 4 * g;

  f32x16 acc2;
#pragma unroll
  for (int r = 0; r < 16; ++r) acc2[r] = 0.f;

  for (int hh = 0; hh < 4; ++hh) {
    const int h = hg * 4 + hh;
    {
      const short* pa = VALShi + ((size_t)(i0 + tn) << 9) + h * 64 + k8 * 16;
      const short* pl = VALSlo + ((size_t)(i0 + tn) << 9) + h * 64 + k8 * 16;
      *(int4*)&AH[k8][tn][0] = *(const int4*)pa;
      *(int4*)&AH[k8][tn][8] = *(const int4*)(pa + 8);
      *(int4*)&AL[k8][tn][0] = *(const int4*)pl;
      *(int4*)&AL[k8][tn][8] = *(const int4*)(pl + 8);
      const short* pb  = W2thi + (size_t)h * 4096 + tn * 64 + k8 * 16;
      const short* pbl = W2tlo + (size_t)h * 4096 + tn * 64 + k8 * 16;
      *(int4*)&BH[k8][tn][0] = *(const int4*)pb;
      *(int4*)&BH[k8][tn][8] = *(const int4*)(pb + 8);
      *(int4*)&BL[k8][tn][0] = *(const int4*)pbl;
      *(int4*)&BL[k8][tn][8] = *(const int4*)(pbl + 8);
      const short* pd  = Wo1thi + (size_t)tn * FDIM + h * 64 + k8 * 16;
      const short* pdl = Wo1tlo + (size_t)tn * FDIM + h * 64 + k8 * 16;
      *(int4*)&DH[k8][tn][0] = *(const int4*)pd;
      *(int4*)&DH[k8][tn][8] = *(const int4*)(pd + 8);
      *(int4*)&DL[k8][tn][0] = *(const int4*)pdl;
      *(int4*)&DL[k8][tn][8] = *(const int4*)(pdl + 8);
    }
    __syncthreads();
    // W2 MFMA (K=64)
    f32x16 accw;
#pragma unroll
    for (int r = 0; r < 16; ++r) accw[r] = 0.f;
#pragma unroll
    for (int t = 0; t < 4; ++t) {
      bf16x8 ah = *(const bf16x8*)&AH[t][wm * 32 + ml][g8];
      bf16x8 al = *(const bf16x8*)&AL[t][wm * 32 + ml][g8];
      bf16x8 bh = *(const bf16x8*)&BH[t][wn * 32 + ml][g8];
      bf16x8 bl = *(const bf16x8*)&BL[t][wn * 32 + ml][g8];
      accw = __builtin_amdgcn_mfma_f32_32x32x16_bf16(ah, bh, accw, 0, 0, 0);
      accw = __builtin_amdgcn_mfma_f32_32x32x16_bf16(al, bh, accw, 0, 0, 0);
      accw = __builtin_amdgcn_mfma_f32_32x32x16_bf16(ah, bl, accw, 0, 0, 0);
    }
    const float bwv = bW[h * 64 + colw];
    const int ts = colw >> 4, ss = colw & 15;
#pragma unroll
    for (int r = 0; r < 16; ++r) {
      int rl = rowl0 + (r & 3) + 8 * (r >> 2);
      float v = accw[r] + bwv;
      v = v > 0.f ? v : __expf(v) - 1.f;
      unsigned short hv = f2bf(v);
      CH[ts][rl][ss] = (short)hv;
      CL[ts][rl][ss] = (short)f2bf(v - bf2f(hv));
    }
    __syncthreads();
#pragma unroll
    for (int t = 0; t < 4; ++t) {
      bf16x8 ah = *(const bf16x8*)&CH[t][wm * 32 + ml][g8];
      bf16x8 al = *(const bf16x8*)&CL[t][wm * 32 + ml][g8];
      bf16x8 bh = *(const bf16x8*)&DH[t][wn * 32 + ml][g8];
      bf16x8 bl = *(const bf16x8*)&DL[t][wn * 32 + ml][g8];
      acc2 = __builtin_amdgcn_mfma_f32_32x32x16_bf16(ah, bh, acc2, 0, 0, 0);
      acc2 = __builtin_amdgcn_mfma_f32_32x32x16_bf16(al, bh, acc2, 0, 0, 0);
      acc2 = __builtin_amdgcn_mfma_f32_32x32x16_bf16(ah, bl, acc2, 0, 0, 0);
    }
    __syncthreads();
  }

  // epilogue: partial FTS2 + partial f1o/f2o (no bias)
  float* FTS2p = FTS2 + (size_t)hg * NN * CDIM;
  const bool act = colw < CDIM;
  const float aov1 = act ? ao1[colw] : 0.f;
  const float aov2 = act ? ao2[colw] : 0.f;
#pragma unroll
  for (int r = 0; r < 16; ++r) {
    int rl = rowl0 + (r & 3) + 8 * (r >> 2);
    float v = acc2[r];
    if (act) FTS2p[(size_t)(i0 + rl) * CDIM + colw] = v;
    float p1 = v * aov1, p2 = v * aov2;
#pragma unroll
    for (int o = 1; o < 32; o <<= 1) {
      p1 += __shfl_xor(p1, o);
      p2 += __shfl_xor(p2, o);
    }
    if (ml == 0) {
      p1buf[wn][rl] = p1;
      p2buf[wn][rl] = p2;
    }
  }
  __syncthreads();
  if (tid < 64) {
    F1O[(size_t)hg * NN + i0 + tid] = p1buf[0][tid] + p1buf[1][tid];
    F2O[(size_t)hg * NN + i0 + tid] = p2buf[0][tid] + p2buf[1][tid];
  }
}

// ---------------- Kernel 5: layer-2 attention + output GEMM (sums parts) ----
__global__ __launch_bounds__(256) void k_agg2(
    const float* __restrict__ FTS2, const float* __restrict__ F1O,
    const float* __restrict__ F2O, const int* __restrict__ nbr,
    const int* __restrict__ cnt, const float* __restrict__ Wo2,
    const float* __restrict__ bo, const float* __restrict__ bo1s,
    const float* __restrict__ bo2s, float* __restrict__ out) {
  int i = blockIdx.x * 4 + (threadIdx.x >> 6);
  int lane = threadIdx.x & 63;
  int deg = cnt[i];
  const int* nb = nbr + (size_t)i * MAXD;
  const float* F2Ob = F2O + NN;
  const float* FTS2b = FTS2 + (size_t)NN * CDIM;
  float f1ib = F1O[i] + F1O[NN + i] + bo1s[0] + bo2s[0];

  int jreg[4];
  float p[4];
  float m = -1e30f;
#pragma unroll
  for (int r = 0; r < 4; ++r) { jreg[r] = 0; p[r] = -1e30f; }
#pragma unroll
  for (int r = 0; r < 4; ++r) {
    int t = r * 64 + lane;
    if (t < deg) {
      int j = nb[t];
      jreg[r] = j;
      float x = f1ib + F2O[j] + F2Ob[j];
      x = x >= 0.f ? x : 0.2f * x;
      p[r] = x;
      m = fmaxf(m, x);
    }
  }
  m = wave_max64(m);
  float s = 0.f;
#pragma unroll
  for (int r = 0; r < 4; ++r) {
    int t = r * 64 + lane;
    float e = (t < deg) ? __expf(p[r] - m) : 0.f;
    p[r] = e;
    s += e;
  }
  s = wave_sum64(s);

  const bool act = lane < CDIM;
  float accA = 0.f, accB = 0.f, accC = 0.f, accD = 0.f;
#pragma unroll
  for (int r = 0; r < 4; ++r) {
    int base = r * 64;
    if (base >= deg) break;
    int lim = deg - base;
    lim = lim < 64 ? lim : 64;
    int sl = 0;
    for (; sl + 4 <= lim; sl += 4) {
      float w0 = readlane_f(p[r], sl);
      float w1 = readlane_f(p[r], sl + 1);
      float w2 = readlane_f(p[r], sl + 2);
      float w3 = readlane_f(p[r], sl + 3);
      int j0 = readlane_i(jreg[r], sl);
      int j1 = readlane_i(jreg[r], sl + 1);
      int j2 = readlane_i(jreg[r], sl + 2);
      int j3 = readlane_i(jreg[r], sl + 3);
      float f0 = act ? (FTS2[(size_t)j0 * CDIM + lane] + FTS2b[(size_t)j0 * CDIM + lane]) : 0.f;
      float f1 = act ? (FTS2[(size_t)j1 * CDIM + lane] + FTS2b[(size_t)j1 * CDIM + lane]) : 0.f;
      float f2 = act ? (FTS2[(size_t)j2 * CDIM + lane] + FTS2b[(size_t)j2 * CDIM + lane]) : 0.f;
      float f3 = act ? (FTS2[(size_t)j3 * CDIM + lane] + FTS2b[(size_t)j3 * CDIM + lane]) : 0.f;
      accA += w0 * f0;
      accB += w1 * f1;
      accC += w2 * f2;
      accD += w3 * f3;
    }
    for (; sl < lim; ++sl) {
      float w0 = readlane_f(p[r], sl);
      int j0 = readlane_i(jreg[r], sl);
      float f0 = act ? (FTS2[(size_t)j0 * CDIM + lane] + FTS2b[(size_t)j0 * CDIM + lane]) : 0.f;
      accA += w0 * f0;
    }
  }
  float v = (accA + accB + accC + accD) / s;

  float o = act ? bo[lane] : 0.f;
  for (int kk = 0; kk < CDIM; ++kk) {
    float w = readlane_f(v, kk);
    float b = act ? Wo2[kk * CDIM + lane] : 0.f;
    o += w * b;
  }
  if (act) out[(size_t)i * CDIM + lane] = o;
}

extern "C" void kernel_launch(void* const* d_in, const int* in_sizes, int n_in,
                              void* d_out, int out_size, void* d_ws, size_t ws_size,
                              hipStream_t stream) {
  const float* seq  = (const float*)d_in[0];
  const float* bias = (const float*)d_in[1];
  const float* W1   = (const float*)d_in[2];
  const float* a1   = (const float*)d_in[3];
  const float* b1   = (const float*)d_in[4];
  const float* a2   = (const float*)d_in[5];
  const float* b2   = (const float*)d_in[6];
  const float* W2   = (const float*)d_in[7];
  const float* bW   = (const float*)d_in[8];
  const float* Wo1  = (const float*)d_in[9];
  const float* ao1  = (const float*)d_in[10];
  const float* bo1  = (const float*)d_in[11];
  const float* ao2  = (const float*)d_in[12];
  const float* bo2  = (const float*)d_in[13];
  const float* Wo2  = (const float*)d_in[14];
  const float* bo   = (const float*)d_in[15];
  float* out = (float*)d_out;

  float* ws    = (float*)d_ws;
  float* F1t   = ws;                          // N*8
  float* F2t   = F1t  + (size_t)NN * NHEAD;   // N*8
  float* FTS2  = F2t  + (size_t)NN * NHEAD;   // 2*N*40 (two head-group parts)
  float* F1O   = FTS2 + (size_t)2 * NN * CDIM; // 2*N
  float* F2O   = F1O  + 2 * NN;               // 2*N
  short* FTSb  = (short*)(F2O + 2 * NN);      // N*512 bf16
  short* Bhi   = FTSb + (size_t)NN * FDIM;    // 8*64*512
  short* Blo   = Bhi + (size_t)NHEAD * HDIM * FDIM;
  short* VALShi= Blo + (size_t)NHEAD * HDIM * FDIM;  // N*512
  short* VALSlo= VALShi + (size_t)NN * FDIM;
  short* W2thi = VALSlo + (size_t)NN * FDIM;         // 8*64*64
  short* W2tlo = W2thi + (size_t)NHEAD * HDIM * HDIM;
  short* Wo1thi= W2tlo + (size_t)NHEAD * HDIM * HDIM; // 64*512
  short* Wo1tlo= Wo1thi + (size_t)64 * FDIM;
  int*   nbr   = (int*)(Wo1tlo + (size_t)64 * FDIM);  // N*MAXD
  int*   cnt   = nbr + (size_t)NN * MAXD;     // N

  // 1. weight conversions
  k_prep<<<64 + 8 + 8, 256, 0, stream>>>(
      W1, Bhi, Blo, W2, W2thi, W2tlo, Wo1, Wo1thi, Wo1tlo);
  // 2. MFMA GEMM (BK=32, 24KB LDS, in-reg seq cvt) + f1/f2  ∥  CSR build
  k_gemm<<<256 + NN, 256, 0, stream>>>(
      seq, Bhi, Blo, a1, b1, a2, b2, FTSb, F1t, F2t, bias, nbr, cnt);
  // 3. sparse softmax + aggregation (1 wave/row, 16B gathers, ILP4)
  k_agg1<<<NN / 4, 256, 0, stream>>>(FTSb, F1t, F2t, nbr, cnt, VALShi, VALSlo);
  // 4. split tail (2 head-groups x 64 row-tiles = 128 blocks)
  k_tail<<<NN / 64 * 2, 256, 0, stream>>>(VALShi, VALSlo, W2thi, W2tlo, bW,
                                          Wo1thi, Wo1tlo, ao1, ao2,
                                          FTS2, F1O, F2O);
  // 5. layer-2 sparse attention (sums tail parts) + final dense + bias
  k_agg2<<<NN / 4, 256, 0, stream>>>(FTS2, F1O, F2O, nbr, cnt, Wo2, bo,
                                     bo1, bo2, out);
}

// Round 18
// 83.110 us; speedup vs baseline: 1.0167x; 1.0167x over previous
//
#include <hip/hip_runtime.h>
#include <cstdint>
#include <cstddef>

#define NN 4096
#define FDIM 512
#define HDIM 64
#define NHEAD 8
#define CDIM 40
#define MAXD 256   // max neighbors kept per row (~41 expected)

typedef __attribute__((ext_vector_type(8))) short bf16x8;
typedef __attribute__((ext_vector_type(16))) float f32x16;

__device__ __forceinline__ float wave_max64(float v) {
  for (int o = 32; o; o >>= 1) v = fmaxf(v, __shfl_xor(v, o));
  return v;
}
__device__ __forceinline__ float wave_sum64(float v) {
  for (int o = 32; o; o >>= 1) v += __shfl_xor(v, o);
  return v;
}
__device__ __forceinline__ float readlane_f(float v, int sl) {
  return __uint_as_float((unsigned)__builtin_amdgcn_readlane((int)__float_as_uint(v), sl));
}
__device__ __forceinline__ int readlane_i(int v, int sl) {
  return __builtin_amdgcn_readlane(v, sl);
}
// fp32 -> bf16 (RNE) and back, via bit ops
__device__ __forceinline__ unsigned short f2bf(float x) {
  unsigned u = __float_as_uint(x);
  return (unsigned short)((u + 0x7fffu + ((u >> 16) & 1u)) >> 16);
}
__device__ __forceinline__ float bf2f(unsigned short b) {
  return __uint_as_float(((unsigned)b) << 16);
}
// unpack packed bf16 pair (int) -> floats
__device__ __forceinline__ float lo16f(int u) { return __int_as_float(u << 16); }
__device__ __forceinline__ float hi16f(int u) { return __int_as_float(u & 0xffff0000); }
// 8 fp32 -> 8 bf16 hi + 8 bf16 lo, packed
__device__ __forceinline__ void cvt8(const float4& a, const float4& b,
                                     int4& hi, int4& lo) {
  unsigned short h0 = f2bf(a.x), h1 = f2bf(a.y), h2 = f2bf(a.z), h3 = f2bf(a.w);
  unsigned short h4 = f2bf(b.x), h5 = f2bf(b.y), h6 = f2bf(b.z), h7 = f2bf(b.w);
  hi = make_int4((int)((unsigned)h0 | ((unsigned)h1 << 16)),
                 (int)((unsigned)h2 | ((unsigned)h3 << 16)),
                 (int)((unsigned)h4 | ((unsigned)h5 << 16)),
                 (int)((unsigned)h6 | ((unsigned)h7 << 16)));
  unsigned short l0 = f2bf(a.x - bf2f(h0)), l1 = f2bf(a.y - bf2f(h1));
  unsigned short l2 = f2bf(a.z - bf2f(h2)), l3 = f2bf(a.w - bf2f(h3));
  unsigned short l4 = f2bf(b.x - bf2f(h4)), l5 = f2bf(b.y - bf2f(h5));
  unsigned short l6 = f2bf(b.z - bf2f(h6)), l7 = f2bf(b.w - bf2f(h7));
  lo = make_int4((int)((unsigned)l0 | ((unsigned)l1 << 16)),
                 (int)((unsigned)l2 | ((unsigned)l3 << 16)),
                 (int)((unsigned)l4 | ((unsigned)l5 << 16)),
                 (int)((unsigned)l6 | ((unsigned)l7 << 16)));
}

// ---------------- Kernel 1: prep (weight conversions only) -----------------
__global__ __launch_bounds__(256) void k_prep(
    const float* __restrict__ W1, short* __restrict__ Bhi, short* __restrict__ Blo,
    const float* __restrict__ W2, short* __restrict__ W2thi, short* __restrict__ W2tlo,
    const float* __restrict__ Wo1, short* __restrict__ Wo1thi, short* __restrict__ Wo1tlo) {
  __shared__ float T[64][65];
  int bx = blockIdx.x, tid = threadIdx.x;
  if (bx < 64) {       // ---- W1 tile transpose + bf16 hi/lo: [k][n] -> [n][k]
    int h = bx >> 3, kb = bx & 7;
    const float* src = W1 + ((size_t)h * FDIM + kb * 64) * HDIM;
#pragma unroll
    for (int q = 0; q < 4; ++q) {
      int fi = q * 256 + tid, kk = fi >> 4, n4 = fi & 15;
      float4 v = *(const float4*)(src + (size_t)kk * HDIM + n4 * 4);
      T[n4 * 4 + 0][kk] = v.x; T[n4 * 4 + 1][kk] = v.y;
      T[n4 * 4 + 2][kk] = v.z; T[n4 * 4 + 3][kk] = v.w;
    }
    __syncthreads();
#pragma unroll
    for (int q = 0; q < 4; ++q) {
      int fi = q * 256 + tid, n = fi >> 4, k4 = fi & 15;
      float a = T[n][k4 * 4], b = T[n][k4 * 4 + 1];
      float c = T[n][k4 * 4 + 2], d = T[n][k4 * 4 + 3];
      size_t o = ((size_t)h * 64 + n) * FDIM + kb * 64 + k4 * 4;
      unsigned short ha = f2bf(a), hb = f2bf(b), hc = f2bf(c), hd = f2bf(d);
      *(short4*)(Bhi + o) = make_short4((short)ha, (short)hb, (short)hc, (short)hd);
      *(short4*)(Blo + o) = make_short4((short)f2bf(a - bf2f(ha)), (short)f2bf(b - bf2f(hb)),
                                        (short)f2bf(c - bf2f(hc)), (short)f2bf(d - bf2f(hd)));
    }
    return;
  }
  bx -= 64;
  if (bx < 8) {        // ---- W2[h] transpose [64k][64n] -> [n][k] hi/lo
    int h = bx;
    const float* src = W2 + (size_t)h * HDIM * HDIM;
#pragma unroll
    for (int q = 0; q < 4; ++q) {
      int fi = q * 256 + tid, kk = fi >> 4, n4 = fi & 15;
      float4 v = *(const float4*)(src + (size_t)kk * HDIM + n4 * 4);
      T[n4 * 4 + 0][kk] = v.x; T[n4 * 4 + 1][kk] = v.y;
      T[n4 * 4 + 2][kk] = v.z; T[n4 * 4 + 3][kk] = v.w;
    }
    __syncthreads();
#pragma unroll
    for (int q = 0; q < 4; ++q) {
      int fi = q * 256 + tid, n = fi >> 4, k4 = fi & 15;
      float a = T[n][k4 * 4], b = T[n][k4 * 4 + 1];
      float c = T[n][k4 * 4 + 2], d = T[n][k4 * 4 + 3];
      size_t o = (size_t)h * 4096 + (size_t)n * 64 + k4 * 4;
      unsigned short ha = f2bf(a), hb = f2bf(b), hc = f2bf(c), hd = f2bf(d);
      *(short4*)(W2thi + o) = make_short4((short)ha, (short)hb, (short)hc, (short)hd);
      *(short4*)(W2tlo + o) = make_short4((short)f2bf(a - bf2f(ha)), (short)f2bf(b - bf2f(hb)),
                                          (short)f2bf(c - bf2f(hc)), (short)f2bf(d - bf2f(hd)));
    }
    return;
  }
  bx -= 8;
  {                    // ---- Wo1 transpose+pad [512][40] -> [64][512] hi/lo
#pragma unroll
    for (int q = 0; q < 16; ++q) {
      int idx = q * 256 + tid;          // 0..4095
      int n = bx * 8 + (idx >> 9), k = idx & 511;
      float v = (n < CDIM) ? Wo1[(size_t)k * CDIM + n] : 0.f;
      unsigned short hv = f2bf(v);
      Wo1thi[(size_t)n * FDIM + k] = (short)hv;
      Wo1tlo[(size_t)n * FDIM + k] = (short)f2bf(v - bf2f(hv));
    }
  }
}

// ---------------- Kernel 2: MFMA GEMM (in-reg seq cvt) + f1/f2  ∥  CSR -----
__global__ __launch_bounds__(256) void k_gemm(
    const float* __restrict__ seq,
    const short* __restrict__ Bhi, const short* __restrict__ Blo,
    const float* __restrict__ a1, const float* __restrict__ b1,
    const float* __restrict__ a2, const float* __restrict__ b2,
    short* __restrict__ FTSb, float* __restrict__ F1t, float* __restrict__ F2t,
    const float* __restrict__ bias, int* __restrict__ nbr, int* __restrict__ cnt) {
  __shared__ short AH[4][64][16], AL[4][64][16];    // [kstep16][m][k-slot]
  __shared__ short BH[4][128][16], BL[4][128][16];  // [kstep16][n][k-slot]
  __shared__ int wtot[4];
  const int bx = blockIdx.x;
  const int tid = threadIdx.x, lane = tid & 63, w = tid >> 6;

  if (bx >= 256) {     // ---------------- CSR: one block per row ------------
    int row = bx - 256;
    int wv = w;
    const float4* r = (const float4*)(bias + (size_t)row * NN);
    unsigned mask = 0;
#pragma unroll
    for (int i = 0; i < 4; ++i) {
      float4 v = r[tid * 4 + i];
      mask |= (unsigned)((v.x == 0.f ? 1 : 0) | (v.y == 0.f ? 2 : 0) |
                         (v.z == 0.f ? 4 : 0) | (v.w == 0.f ? 8 : 0)) << (i * 4);
    }
    int c = __popc(mask);
    int pre = c;
#pragma unroll
    for (int o = 1; o < 64; o <<= 1) {
      int u = __shfl_up(pre, o);
      if (lane >= o) pre += u;
    }
    if (lane == 63) wtot[wv] = pre;
    __syncthreads();
    int woff = 0;
#pragma unroll
    for (int ww = 0; ww < 4; ++ww)
      if (ww < wv) woff += wtot[ww];
    int excl = woff + pre - c;
    int* outp = nbr + (size_t)row * MAXD;
    int col0 = tid * 16, k = 0;
#pragma unroll
    for (int i = 0; i < 16; ++i) {
      if ((mask >> i) & 1) {
        int p = excl + k;
        if (p < MAXD) outp[p] = col0 + i;
        ++k;
      }
    }
    if (tid == 0) {
      int total = wtot[0] + wtot[1] + wtot[2] + wtot[3];
      cnt[row] = total < MAXD ? total : MAXD;
    }
    return;
  }

  // ---------------- GEMM tile ----------------
  const int mtile = bx & 63, npair = bx >> 6;
  const int wm = w >> 1, wn = w & 1;
  const int ml = lane & 31, g = lane >> 5, g8 = g * 8;

  f32x16 acc0, acc1;
#pragma unroll
  for (int r = 0; r < 16; ++r) { acc0[r] = 0.f; acc1[r] = 0.f; }

  const short* Bbh = Bhi + (((size_t)npair * 128) << 9);
  const short* Bbl = Blo + (((size_t)npair * 128) << 9);

  const int tn = tid >> 3, k8 = tid & 7;
  const int ks = k8 >> 1, ko = (k8 & 1) * 8;
  const size_t so = ((size_t)tn << 9) + (size_t)k8 * 8;
  const float* As0 = seq + (((size_t)(mtile * 64 + tn)) << 9) + k8 * 8;
  const float* As1 = As0 + ((size_t)32 << 9);

  float4 fa0a, fa0b, fa1a, fa1b;
  int4 rbh0, rbh1, rbh2, rbh3, rbl0, rbl1, rbl2, rbl3;
  {
    fa0a = *(const float4*)(As0);      fa0b = *(const float4*)(As0 + 4);
    fa1a = *(const float4*)(As1);      fa1b = *(const float4*)(As1 + 4);
    rbh0 = *(const int4*)(Bbh + so);              rbl0 = *(const int4*)(Bbl + so);
    rbh1 = *(const int4*)(Bbh + so + (32 << 9));  rbl1 = *(const int4*)(Bbl + so + (32 << 9));
    rbh2 = *(const int4*)(Bbh + so + (64 << 9));  rbl2 = *(const int4*)(Bbl + so + (64 << 9));
    rbh3 = *(const int4*)(Bbh + so + (96 << 9));  rbl3 = *(const int4*)(Bbl + so + (96 << 9));
  }

  const int NCH = FDIM / 64;   // 8 chunks
  for (int c = 0; c < NCH; ++c) {
    {
      int4 hi0, lo0, hi1, lo1;
      cvt8(fa0a, fa0b, hi0, lo0);
      cvt8(fa1a, fa1b, hi1, lo1);
      *(int4*)&AH[ks][tn][ko] = hi0;       *(int4*)&AL[ks][tn][ko] = lo0;
      *(int4*)&AH[ks][32 + tn][ko] = hi1;  *(int4*)&AL[ks][32 + tn][ko] = lo1;
    }
    *(int4*)&BH[ks][tn][ko] = rbh0;       *(int4*)&BL[ks][tn][ko] = rbl0;
    *(int4*)&BH[ks][32 + tn][ko] = rbh1;  *(int4*)&BL[ks][32 + tn][ko] = rbl1;
    *(int4*)&BH[ks][64 + tn][ko] = rbh2;  *(int4*)&BL[ks][64 + tn][ko] = rbl2;
    *(int4*)&BH[ks][96 + tn][ko] = rbh3;  *(int4*)&BL[ks][96 + tn][ko] = rbl3;
    __syncthreads();
    if (c + 1 < NCH) {
      size_t o = so + (size_t)(c + 1) * 64;
      const float* a0 = As0 + (size_t)(c + 1) * 64;
      const float* a1p = As1 + (size_t)(c + 1) * 64;
      fa0a = *(const float4*)(a0);      fa0b = *(const float4*)(a0 + 4);
      fa1a = *(const float4*)(a1p);     fa1b = *(const float4*)(a1p + 4);
      rbh0 = *(const int4*)(Bbh + o);              rbl0 = *(const int4*)(Bbl + o);
      rbh1 = *(const int4*)(Bbh + o + (32 << 9));  rbl1 = *(const int4*)(Bbl + o + (32 << 9));
      rbh2 = *(const int4*)(Bbh + o + (64 << 9));  rbl2 = *(const int4*)(Bbl + o + (64 << 9));
      rbh3 = *(const int4*)(Bbh + o + (96 << 9));  rbl3 = *(const int4*)(Bbl + o + (96 << 9));
    }
#pragma unroll
    for (int t = 0; t < 4; ++t) {
      bf16x8 ah = *(const bf16x8*)&AH[t][wm * 32 + ml][g8];
      bf16x8 al = *(const bf16x8*)&AL[t][wm * 32 + ml][g8];
      bf16x8 bh0 = *(const bf16x8*)&BH[t][wn * 64 + ml][g8];
      bf16x8 bl0 = *(const bf16x8*)&BL[t][wn * 64 + ml][g8];
      acc0 = __builtin_amdgcn_mfma_f32_32x32x16_bf16(ah, bh0, acc0, 0, 0, 0);
      acc0 = __builtin_amdgcn_mfma_f32_32x32x16_bf16(al, bh0, acc0, 0, 0, 0);
      acc0 = __builtin_amdgcn_mfma_f32_32x32x16_bf16(ah, bl0, acc0, 0, 0, 0);
      bf16x8 bh1 = *(const bf16x8*)&BH[t][wn * 64 + 32 + ml][g8];
      bf16x8 bl1 = *(const bf16x8*)&BL[t][wn * 64 + 32 + ml][g8];
      acc1 = __builtin_amdgcn_mfma_f32_32x32x16_bf16(ah, bh1, acc1, 0, 0, 0);
      acc1 = __builtin_amdgcn_mfma_f32_32x32x16_bf16(al, bh1, acc1, 0, 0, 0);
      acc1 = __builtin_amdgcn_mfma_f32_32x32x16_bf16(ah, bl1, acc1, 0, 0, 0);
    }
    __syncthreads();
  }

  // epilogue: C layout col=lane&31, row=(r&3)+8*(r>>2)+4*(lane>>5)
  const int h = npair * 2 + wn;
  const float a1lo = a1[h * 64 + ml], a1hi = a1[h * 64 + 32 + ml];
  const float a2lo = a2[h * 64 + ml], a2hi = a2[h * 64 + 32 + ml];
  const float b1h = b1[h], b2h = b2[h];
  const int row0 = mtile * 64 + wm * 32 + 4 * g;
  const int col0 = npair * 128 + wn * 64 + ml;
#pragma unroll
  for (int r = 0; r < 16; ++r) {
    int row = row0 + (r & 3) + 8 * (r >> 2);
    FTSb[(size_t)row * FDIM + col0] = (short)f2bf(acc0[r]);
    FTSb[(size_t)row * FDIM + col0 + 32] = (short)f2bf(acc1[r]);
    float p1 = acc0[r] * a1lo + acc1[r] * a1hi;
    float p2 = acc0[r] * a2lo + acc1[r] * a2hi;
#pragma unroll
    for (int o = 1; o < 32; o <<= 1) {
      p1 += __shfl_xor(p1, o);
      p2 += __shfl_xor(p2, o);
    }
    if (ml == 0) {
      F1t[(size_t)row * 8 + h] = p1 + b1h;
      F2t[(size_t)row * 8 + h] = p2 + b2h;
    }
  }
}

// ---------------- Kernel 3: sparse softmax + aggregation (1 wave/row) -------
__global__ __launch_bounds__(256) void k_agg1(
    const short* __restrict__ FTSb, const float* __restrict__ F1t,
    const float* __restrict__ F2t, const int* __restrict__ nbr,
    const int* __restrict__ cnt, short* __restrict__ VALShi,
    short* __restrict__ VALSlo) {
  __shared__ float plds[4][MAXD][8];   // [wave][slot][head] = 32 KB
  int wv = threadIdx.x >> 6, lane = threadIdx.x & 63;
  int i = blockIdx.x * 4 + wv;
  int deg = cnt[i];
  const int* nb = nbr + (size_t)i * MAXD;
  float4 f1a = *(const float4*)(F1t + (size_t)i * 8);
  float4 f1b = *(const float4*)(F1t + (size_t)i * 8 + 4);

  float4 pa[4], pb[4];
  int jreg[4];
  float m0 = -1e30f, m1 = -1e30f, m2 = -1e30f, m3 = -1e30f;
  float m4 = -1e30f, m5 = -1e30f, m6 = -1e30f, m7 = -1e30f;
#pragma unroll
  for (int r = 0; r < 4; ++r) {
    int t = r * 64 + lane;
    jreg[r] = 0;
    pa[r] = make_float4(-1e30f, -1e30f, -1e30f, -1e30f);
    pb[r] = pa[r];
    if (t < deg) {
      int j = nb[t];
      jreg[r] = j;
      float4 f2a = *(const float4*)(F2t + (size_t)j * 8);
      float4 f2b = *(const float4*)(F2t + (size_t)j * 8 + 4);
      float4 xa, xb;
      xa.x = f1a.x + f2a.x; xa.x = xa.x >= 0.f ? xa.x : 0.2f * xa.x;
      xa.y = f1a.y + f2a.y; xa.y = xa.y >= 0.f ? xa.y : 0.2f * xa.y;
      xa.z = f1a.z + f2a.z; xa.z = xa.z >= 0.f ? xa.z : 0.2f * xa.z;
      xa.w = f1a.w + f2a.w; xa.w = xa.w >= 0.f ? xa.w : 0.2f * xa.w;
      xb.x = f1b.x + f2b.x; xb.x = xb.x >= 0.f ? xb.x : 0.2f * xb.x;
      xb.y = f1b.y + f2b.y; xb.y = xb.y >= 0.f ? xb.y : 0.2f * xb.y;
      xb.z = f1b.z + f2b.z; xb.z = xb.z >= 0.f ? xb.z : 0.2f * xb.z;
      xb.w = f1b.w + f2b.w; xb.w = xb.w >= 0.f ? xb.w : 0.2f * xb.w;
      pa[r] = xa; pb[r] = xb;
      m0 = fmaxf(m0, xa.x); m1 = fmaxf(m1, xa.y);
      m2 = fmaxf(m2, xa.z); m3 = fmaxf(m3, xa.w);
      m4 = fmaxf(m4, xb.x); m5 = fmaxf(m5, xb.y);
      m6 = fmaxf(m6, xb.z); m7 = fmaxf(m7, xb.w);
    }
  }
  m0 = wave_max64(m0); m1 = wave_max64(m1); m2 = wave_max64(m2); m3 = wave_max64(m3);
  m4 = wave_max64(m4); m5 = wave_max64(m5); m6 = wave_max64(m6); m7 = wave_max64(m7);
  float s0 = 0.f, s1 = 0.f, s2 = 0.f, s3 = 0.f, s4 = 0.f, s5 = 0.f, s6 = 0.f, s7 = 0.f;
#pragma unroll
  for (int r = 0; r < 4; ++r) {
    int t = r * 64 + lane;
    float4 ea = make_float4(0.f, 0.f, 0.f, 0.f), eb = ea;
    if (t < deg) {
      ea.x = __expf(pa[r].x - m0); ea.y = __expf(pa[r].y - m1);
      ea.z = __expf(pa[r].z - m2); ea.w = __expf(pa[r].w - m3);
      eb.x = __expf(pb[r].x - m4); eb.y = __expf(pb[r].y - m5);
      eb.z = __expf(pb[r].z - m6); eb.w = __expf(pb[r].w - m7);
      *(float4*)&plds[wv][t][0] = ea;
      *(float4*)&plds[wv][t][4] = eb;
    }
    s0 += ea.x; s1 += ea.y; s2 += ea.z; s3 += ea.w;
    s4 += eb.x; s5 += eb.y; s6 += eb.z; s7 += eb.w;
  }
  s0 = wave_sum64(s0); s1 = wave_sum64(s1); s2 = wave_sum64(s2); s3 = wave_sum64(s3);
  s4 = wave_sum64(s4); s5 = wave_sum64(s5); s6 = wave_sum64(s6); s7 = wave_sum64(s7);

  const int q = lane >> 3;   // head for this lane's 8 features
  float sq = (q < 4) ? (q < 2 ? (q == 0 ? s0 : s1) : (q == 2 ? s2 : s3))
                     : (q < 6 ? (q == 4 ? s4 : s5) : (q == 6 ? s6 : s7));
  float inv = 1.f / sq;

  float4 aA = make_float4(0.f, 0.f, 0.f, 0.f), bA = aA;
  float4 aB = aA, bB = aA, aC = aA, bC = aA, aD = aA, bD = aA;
  const size_t lo8 = (size_t)lane * 8;
#pragma unroll
  for (int r = 0; r < 4; ++r) {
    int base = r * 64;
    if (base >= deg) break;
    int lim = deg - base;
    lim = lim < 64 ? lim : 64;
    int sl = 0;
    for (; sl + 4 <= lim; sl += 4) {
      int j0 = readlane_i(jreg[r], sl);
      int j1 = readlane_i(jreg[r], sl + 1);
      int j2 = readlane_i(jreg[r], sl + 2);
      int j3 = readlane_i(jreg[r], sl + 3);
      float w0 = plds[wv][base + sl][q];
      float w1 = plds[wv][base + sl + 1][q];
      float w2 = plds[wv][base + sl + 2][q];
      float w3 = plds[wv][base + sl + 3][q];
      int4 g0 = *(const int4*)(FTSb + (size_t)j0 * FDIM + lo8);
      int4 g1 = *(const int4*)(FTSb + (size_t)j1 * FDIM + lo8);
      int4 g2 = *(const int4*)(FTSb + (size_t)j2 * FDIM + lo8);
      int4 g3 = *(const int4*)(FTSb + (size_t)j3 * FDIM + lo8);
      aA.x += w0 * lo16f(g0.x); aA.y += w0 * hi16f(g0.x);
      aA.z += w0 * lo16f(g0.y); aA.w += w0 * hi16f(g0.y);
      bA.x += w0 * lo16f(g0.z); bA.y += w0 * hi16f(g0.z);
      bA.z += w0 * lo16f(g0.w); bA.w += w0 * hi16f(g0.w);
      aB.x += w1 * lo16f(g1.x); aB.y += w1 * hi16f(g1.x);
      aB.z += w1 * lo16f(g1.y); aB.w += w1 * hi16f(g1.y);
      bB.x += w1 * lo16f(g1.z); bB.y += w1 * hi16f(g1.z);
      bB.z += w1 * lo16f(g1.w); bB.w += w1 * hi16f(g1.w);
      aC.x += w2 * lo16f(g2.x); aC.y += w2 * hi16f(g2.x);
      aC.z += w2 * lo16f(g2.y); aC.w += w2 * hi16f(g2.y);
      bC.x += w2 * lo16f(g2.z); bC.y += w2 * hi16f(g2.z);
      bC.z += w2 * lo16f(g2.w); bC.w += w2 * hi16f(g2.w);
      aD.x += w3 * lo16f(g3.x); aD.y += w3 * hi16f(g3.x);
      aD.z += w3 * lo16f(g3.y); aD.w += w3 * hi16f(g3.y);
      bD.x += w3 * lo16f(g3.z); bD.y += w3 * hi16f(g3.z);
      bD.z += w3 * lo16f(g3.w); bD.w += w3 * hi16f(g3.w);
    }
    for (; sl < lim; ++sl) {
      int j0 = readlane_i(jreg[r], sl);
      float w0 = plds[wv][base + sl][q];
      int4 g0 = *(const int4*)(FTSb + (size_t)j0 * FDIM + lo8);
      aA.x += w0 * lo16f(g0.x); aA.y += w0 * hi16f(g0.x);
      aA.z += w0 * lo16f(g0.y); aA.w += w0 * hi16f(g0.y);
      bA.x += w0 * lo16f(g0.z); bA.y += w0 * hi16f(g0.z);
      bA.z += w0 * lo16f(g0.w); bA.w += w0 * hi16f(g0.w);
    }
  }
  float v0 = (aA.x + aB.x + aC.x + aD.x) * inv;
  float v1 = (aA.y + aB.y + aC.y + aD.y) * inv;
  float v2 = (aA.z + aB.z + aC.z + aD.z) * inv;
  float v3 = (aA.w + aB.w + aC.w + aD.w) * inv;
  float v4 = (bA.x + bB.x + bC.x + bD.x) * inv;
  float v5 = (bA.y + bB.y + bC.y + bD.y) * inv;
  float v6 = (bA.z + bB.z + bC.z + bD.z) * inv;
  float v7 = (bA.w + bB.w + bC.w + bD.w) * inv;
  unsigned short h0 = f2bf(v0), h1 = f2bf(v1), h2 = f2bf(v2), h3 = f2bf(v3);
  unsigned short h4 = f2bf(v4), h5 = f2bf(v5), h6 = f2bf(v6), h7 = f2bf(v7);
  *(int4*)(VALShi + (size_t)i * FDIM + lo8) = make_int4(
      (int)((unsigned)h0 | ((unsigned)h1 << 16)), (int)((unsigned)h2 | ((unsigned)h3 << 16)),
      (int)((unsigned)h4 | ((unsigned)h5 << 16)), (int)((unsigned)h6 | ((unsigned)h7 << 16)));
  unsigned short l0 = f2bf(v0 - bf2f(h0)), l1 = f2bf(v1 - bf2f(h1));
  unsigned short l2 = f2bf(v2 - bf2f(h2)), l3 = f2bf(v3 - bf2f(h3));
  unsigned short l4 = f2bf(v4 - bf2f(h4)), l5 = f2bf(v5 - bf2f(h5));
  unsigned short l6 = f2bf(v6 - bf2f(h6)), l7 = f2bf(v7 - bf2f(h7));
  *(int4*)(VALSlo + (size_t)i * FDIM + lo8) = make_int4(
      (int)((unsigned)l0 | ((unsigned)l1 << 16)), (int)((unsigned)l2 | ((unsigned)l3 << 16)),
      (int)((unsigned)l4 | ((unsigned)l5 << 16)), (int)((unsigned)l6 | ((unsigned)l7 << 16)));
}

// ---------------- Kernel 4: split tail: per head-group partial FTS2/F1O/F2O -
__global__ __launch_bounds__(256) void k_tail(
    const short* __restrict__ VALShi, const short* __restrict__ VALSlo,
    const short* __restrict__ W2thi, const short* __restrict__ W2tlo,
    const float* __restrict__ bW,
    const short* __restrict__ Wo1thi, const short* __restrict__ Wo1tlo,
    const float* __restrict__ ao1, const float* __restrict__ ao2,
    float* __restrict__ FTS2, float* __restrict__ F1O, float* __restrict__ F2O) {
  __shared__ short AH[4][64][16], AL[4][64][16];   // VALS tile (A of W2 mfma)
  __shared__ short BH[4][64][16], BL[4][64][16];   // W2t[h]    (B of W2 mfma)
  __shared__ short CH[4][64][16], CL[4][64][16];   // H1_h      (A of fts2 mfma)
  __shared__ short DH[4][64][16], DL[4][64][16];   // Wo1t[h]   (B of fts2 mfma)
  __shared__ float p1buf[2][64], p2buf[2][64];
  const int bx = blockIdx.x;
  const int i0 = (bx >> 1) * 64;
  const int hg = bx & 1;
  const int tid = threadIdx.x, lane = tid & 63, w = tid >> 6;
  const int wm = w >> 1, wn = w & 1;
  const int ml = lane & 31, g = lane >> 5, g8 = g * 8;
  const int tn = tid >> 2, k8 = tid & 3;
  const int colw = wn * 32 + ml;
  const int rowl0 = wm * 32 + 4 * g;

  f32x16 acc2;
#pragma unroll
  for (int r = 0; r < 16; ++r) acc2[r] = 0.f;

  for (int hh = 0; hh < 4; ++hh) {
    const int h = hg * 4 + hh;
    {
      const short* pa = VALShi + ((size_t)(i0 + tn) << 9) + h * 64 + k8 * 16;
      const short* pl = VALSlo + ((size_t)(i0 + tn) << 9) + h * 64 + k8 * 16;
      *(int4*)&AH[k8][tn][0] = *(const int4*)pa;
      *(int4*)&AH[k8][tn][8] = *(const int4*)(pa + 8);
      *(int4*)&AL[k8][tn][0] = *(const int4*)pl;
      *(int4*)&AL[k8][tn][8] = *(const int4*)(pl + 8);
      const short* pb  = W2thi + (size_t)h * 4096 + tn * 64 + k8 * 16;
      const short* pbl = W2tlo + (size_t)h * 4096 + tn * 64 + k8 * 16;
      *(int4*)&BH[k8][tn][0] = *(const int4*)pb;
      *(int4*)&BH[k8][tn][8] = *(const int4*)(pb + 8);
      *(int4*)&BL[k8][tn][0] = *(const int4*)pbl;
      *(int4*)&BL[k8][tn][8] = *(const int4*)(pbl + 8);
      const short* pd  = Wo1thi + (size_t)tn * FDIM + h * 64 + k8 * 16;
      const short* pdl = Wo1tlo + (size_t)tn * FDIM + h * 64 + k8 * 16;
      *(int4*)&DH[k8][tn][0] = *(const int4*)pd;
      *(int4*)&DH[k8][tn][8] = *(const int4*)(pd + 8);
      *(int4*)&DL[k8][tn][0] = *(const int4*)pdl;
      *(int4*)&DL[k8][tn][8] = *(const int4*)(pdl + 8);
    }
    __syncthreads();
    // W2 MFMA (K=64)
    f32x16 accw;
#pragma unroll
    for (int r = 0; r < 16; ++r) accw[r] = 0.f;
#pragma unroll
    for (int t = 0; t < 4; ++t) {
      bf16x8 ah = *(const bf16x8*)&AH[t][wm * 32 + ml][g8];
      bf16x8 al = *(const bf16x8*)&AL[t][wm * 32 + ml][g8];
      bf16x8 bh = *(const bf16x8*)&BH[t][wn * 32 + ml][g8];
      bf16x8 bl = *(const bf16x8*)&BL[t][wn * 32 + ml][g8];
      accw = __builtin_amdgcn_mfma_f32_32x32x16_bf16(ah, bh, accw, 0, 0, 0);
      accw = __builtin_amdgcn_mfma_f32_32x32x16_bf16(al, bh, accw, 0, 0, 0);
      accw = __builtin_amdgcn_mfma_f32_32x32x16_bf16(ah, bl, accw, 0, 0, 0);
    }
    const float bwv = bW[h * 64 + colw];
    const int ts = colw >> 4, ss = colw & 15;
#pragma unroll
    for (int r = 0; r < 16; ++r) {
      int rl = rowl0 + (r & 3) + 8 * (r >> 2);
      float v = accw[r] + bwv;
      v = v > 0.f ? v : __expf(v) - 1.f;
      unsigned short hv = f2bf(v);
      CH[ts][rl][ss] = (short)hv;
      CL[ts][rl][ss] = (short)f2bf(v - bf2f(hv));
    }
    __syncthreads();
#pragma unroll
    for (int t = 0; t < 4; ++t) {
      bf16x8 ah = *(const bf16x8*)&CH[t][wm * 32 + ml][g8];
      bf16x8 al = *(const bf16x8*)&CL[t][wm * 32 + ml][g8];
      bf16x8 bh = *(const bf16x8*)&DH[t][wn * 32 + ml][g8];
      bf16x8 bl = *(const bf16x8*)&DL[t][wn * 32 + ml][g8];
      acc2 = __builtin_amdgcn_mfma_f32_32x32x16_bf16(ah, bh, acc2, 0, 0, 0);
      acc2 = __builtin_amdgcn_mfma_f32_32x32x16_bf16(al, bh, acc2, 0, 0, 0);
      acc2 = __builtin_amdgcn_mfma_f32_32x32x16_bf16(ah, bl, acc2, 0, 0, 0);
    }
    __syncthreads();
  }

  // epilogue: partial FTS2 + partial f1o/f2o (no bias)
  float* FTS2p = FTS2 + (size_t)hg * NN * CDIM;
  const bool act = colw < CDIM;
  const float aov1 = act ? ao1[colw] : 0.f;
  const float aov2 = act ? ao2[colw] : 0.f;
#pragma unroll
  for (int r = 0; r < 16; ++r) {
    int rl = rowl0 + (r & 3) + 8 * (r >> 2);
    float v = acc2[r];
    if (act) FTS2p[(size_t)(i0 + rl) * CDIM + colw] = v;
    float p1 = v * aov1, p2 = v * aov2;
#pragma unroll
    for (int o = 1; o < 32; o <<= 1) {
      p1 += __shfl_xor(p1, o);
      p2 += __shfl_xor(p2, o);
    }
    if (ml == 0) {
      p1buf[wn][rl] = p1;
      p2buf[wn][rl] = p2;
    }
  }
  __syncthreads();
  if (tid < 64) {
    F1O[(size_t)hg * NN + i0 + tid] = p1buf[0][tid] + p1buf[1][tid];
    F2O[(size_t)hg * NN + i0 + tid] = p2buf[0][tid] + p2buf[1][tid];
  }
}

// ---------------- Kernel 5: layer-2 attention + output GEMM (sums parts) ----
__global__ __launch_bounds__(256) void k_agg2(
    const float* __restrict__ FTS2, const float* __restrict__ F1O,
    const float* __restrict__ F2O, const int* __restrict__ nbr,
    const int* __restrict__ cnt, const float* __restrict__ Wo2,
    const float* __restrict__ bo, const float* __restrict__ bo1s,
    const float* __restrict__ bo2s, float* __restrict__ out) {
  int i = blockIdx.x * 4 + (threadIdx.x >> 6);
  int lane = threadIdx.x & 63;
  int deg = cnt[i];
  const int* nb = nbr + (size_t)i * MAXD;
  const float* F2Ob = F2O + NN;
  const float* FTS2b = FTS2 + (size_t)NN * CDIM;
  float f1ib = F1O[i] + F1O[NN + i] + bo1s[0] + bo2s[0];

  int jreg[4];
  float p[4];
  float m = -1e30f;
#pragma unroll
  for (int r = 0; r < 4; ++r) { jreg[r] = 0; p[r] = -1e30f; }
#pragma unroll
  for (int r = 0; r < 4; ++r) {
    int t = r * 64 + lane;
    if (t < deg) {
      int j = nb[t];
      jreg[r] = j;
      float x = f1ib + F2O[j] + F2Ob[j];
      x = x >= 0.f ? x : 0.2f * x;
      p[r] = x;
      m = fmaxf(m, x);
    }
  }
  m = wave_max64(m);
  float s = 0.f;
#pragma unroll
  for (int r = 0; r < 4; ++r) {
    int t = r * 64 + lane;
    float e = (t < deg) ? __expf(p[r] - m) : 0.f;
    p[r] = e;
    s += e;
  }
  s = wave_sum64(s);

  const bool act = lane < CDIM;
  float accA = 0.f, accB = 0.f, accC = 0.f, accD = 0.f;
#pragma unroll
  for (int r = 0; r < 4; ++r) {
    int base = r * 64;
    if (base >= deg) break;
    int lim = deg - base;
    lim = lim < 64 ? lim : 64;
    int sl = 0;
    for (; sl + 4 <= lim; sl += 4) {
      float w0 = readlane_f(p[r], sl);
      float w1 = readlane_f(p[r], sl + 1);
      float w2 = readlane_f(p[r], sl + 2);
      float w3 = readlane_f(p[r], sl + 3);
      int j0 = readlane_i(jreg[r], sl);
      int j1 = readlane_i(jreg[r], sl + 1);
      int j2 = readlane_i(jreg[r], sl + 2);
      int j3 = readlane_i(jreg[r], sl + 3);
      float f0 = act ? (FTS2[(size_t)j0 * CDIM + lane] + FTS2b[(size_t)j0 * CDIM + lane]) : 0.f;
      float f1 = act ? (FTS2[(size_t)j1 * CDIM + lane] + FTS2b[(size_t)j1 * CDIM + lane]) : 0.f;
      float f2 = act ? (FTS2[(size_t)j2 * CDIM + lane] + FTS2b[(size_t)j2 * CDIM + lane]) : 0.f;
      float f3 = act ? (FTS2[(size_t)j3 * CDIM + lane] + FTS2b[(size_t)j3 * CDIM + lane]) : 0.f;
      accA += w0 * f0;
      accB += w1 * f1;
      accC += w2 * f2;
      accD += w3 * f3;
    }
    for (; sl < lim; ++sl) {
      float w0 = readlane_f(p[r], sl);
      int j0 = readlane_i(jreg[r], sl);
      float f0 = act ? (FTS2[(size_t)j0 * CDIM + lane] + FTS2b[(size_t)j0 * CDIM + lane]) : 0.f;
      accA += w0 * f0;
    }
  }
  float v = (accA + accB + accC + accD) / s;

  float o = act ? bo[lane] : 0.f;
  for (int kk = 0; kk < CDIM; ++kk) {
    float w = readlane_f(v, kk);
    float b = act ? Wo2[kk * CDIM + lane] : 0.f;
    o += w * b;
  }
  if (act) out[(size_t)i * CDIM + lane] = o;
}

extern "C" void kernel_launch(void* const* d_in, const int* in_sizes, int n_in,
                              void* d_out, int out_size, void* d_ws, size_t ws_size,
                              hipStream_t stream) {
  const float* seq  = (const float*)d_in[0];
  const float* bias = (const float*)d_in[1];
  const float* W1   = (const float*)d_in[2];
  const float* a1   = (const float*)d_in[3];
  const float* b1   = (const float*)d_in[4];
  const float* a2   = (const float*)d_in[5];
  const float* b2   = (const float*)d_in[6];
  const float* W2   = (const float*)d_in[7];
  const float* bW   = (const float*)d_in[8];
  const float* Wo1  = (const float*)d_in[9];
  const float* ao1  = (const float*)d_in[10];
  const float* bo1  = (const float*)d_in[11];
  const float* ao2  = (const float*)d_in[12];
  const float* bo2  = (const float*)d_in[13];
  const float* Wo2  = (const float*)d_in[14];
  const float* bo   = (const float*)d_in[15];
  float* out = (float*)d_out;

  float* ws    = (float*)d_ws;
  float* F1t   = ws;                          // N*8
  float* F2t   = F1t  + (size_t)NN * NHEAD;   // N*8
  float* FTS2  = F2t  + (size_t)NN * NHEAD;   // 2*N*40 (two head-group parts)
  float* F1O   = FTS2 + (size_t)2 * NN * CDIM; // 2*N
  float* F2O   = F1O  + 2 * NN;               // 2*N
  short* FTSb  = (short*)(F2O + 2 * NN);      // N*512 bf16
  short* Bhi   = FTSb + (size_t)NN * FDIM;    // 8*64*512
  short* Blo   = Bhi + (size_t)NHEAD * HDIM * FDIM;
  short* VALShi= Blo + (size_t)NHEAD * HDIM * FDIM;  // N*512
  short* VALSlo= VALShi + (size_t)NN * FDIM;
  short* W2thi = VALSlo + (size_t)NN * FDIM;         // 8*64*64
  short* W2tlo = W2thi + (size_t)NHEAD * HDIM * HDIM;
  short* Wo1thi= W2tlo + (size_t)NHEAD * HDIM * HDIM; // 64*512
  short* Wo1tlo= Wo1thi + (size_t)64 * FDIM;
  int*   nbr   = (int*)(Wo1tlo + (size_t)64 * FDIM);  // N*MAXD
  int*   cnt   = nbr + (size_t)NN * MAXD;     // N

  // 1. weight conversions
  k_prep<<<64 + 8 + 8, 256, 0, stream>>>(
      W1, Bhi, Blo, W2, W2thi, W2tlo, Wo1, Wo1thi, Wo1tlo);
  // 2. MFMA GEMM (BK=64, in-reg seq cvt) + f1/f2  ∥  CSR build
  k_gemm<<<256 + NN, 256, 0, stream>>>(
      seq, Bhi, Blo, a1, b1, a2, b2, FTSb, F1t, F2t, bias, nbr, cnt);
  // 3. sparse softmax + aggregation (1 wave/row, 16B gathers, ILP4)
  k_agg1<<<NN / 4, 256, 0, stream>>>(FTSb, F1t, F2t, nbr, cnt, VALShi, VALSlo);
  // 4. split tail (2 head-groups x 64 row-tiles = 128 blocks)
  k_tail<<<NN / 64 * 2, 256, 0, stream>>>(VALShi, VALSlo, W2thi, W2tlo, bW,
                                          Wo1thi, Wo1tlo, ao1, ao2,
                                          FTS2, F1O, F2O);
  // 5. layer-2 sparse attention (sums tail parts) + final dense + bias
  k_agg2<<<NN / 4, 256, 0, stream>>>(FTS2, F1O, F2O, nbr, cnt, Wo2, bo,
                                     bo1, bo2, out);
}